// Round 5
// baseline (306.898 us; speedup 1.0000x reference)
//
#include <hip/hip_runtime.h>

// MADE / PixelCNN autoregressive inverse (all fp32, per reference):
// one sequential raster decode; each layer computed only at the new pixel
// with cached h0/h1 rows. Bit-exact vs np ref (absmax 0.0, rounds 2-4).
//
// Round-5: rounds 2-4 showed the GCN scheduler targets the LDS-derived
// occupancy (2-3 blocks/CU at 43KB -> 8 waves/EU -> 64-VGPR budget) and
// sinks the 80-float/thread weight arrays into the p-loop as L2 re-reads
// (320 KB/block/step ~ 130us). We only ever run 32 blocks on 256 CUs, so
// multi-block occupancy is worthless: bloat LDS past 80KiB so exactly ONE
// block fits per CU -> 4 waves/EU target -> 128-VGPR budget -> weights stay
// register-resident across the loop.

#define NT 1024

__device__ __forceinline__ float elu(float x) { return x > 0.f ? x : expm1f(x); }

__global__ __launch_bounds__(NT)
__attribute__((amdgpu_waves_per_eu(4, 4)))
void made_ar_decode_k(
    const float* __restrict__ x,
    const float* __restrict__ mw0, const float* __restrict__ mb0,
    const float* __restrict__ mw1, const float* __restrict__ mb1,
    const float* __restrict__ mw2, const float* __restrict__ mb2,
    const float* __restrict__ mwo, const float* __restrict__ mbo,
    const float* __restrict__ lw0, const float* __restrict__ lb0,
    const float* __restrict__ lw1, const float* __restrict__ lb1,
    const float* __restrict__ lw2, const float* __restrict__ lb2,
    const float* __restrict__ lwo, const float* __restrict__ lbo,
    float* __restrict__ out)
{
  const int b    = blockIdx.x;
  const int tid  = threadIdx.x;
  const int role = tid >> 9;          // 0: W1 / h1-partials, 1: W2 / h2-partials
  const int tap  = (tid >> 7) & 3;    // off-center taps NW,N,NE,W
  const int net  = (tid >> 6) & 1;    // 0 = mu, 1 = lv
  const int ch   = tid & 63;

  // tap -> kernel pos (kh,kw) and spatial offset (dr,dc) = (kh-1, kw-1)
  const int kh = (tap < 3) ? 0 : 1;
  const int kw = (tap < 3) ? tap : 0;
  const int dr = (tap < 3) ? -1 : 0;
  const int dc = (tap < 3) ? (tap - 1) : -1;

  __shared__ __align__(16) float yb[9][10][4];       // rows -1..7 -> 0..8, cols -1..8 -> 0..9 (pads stay 0)
  __shared__ __align__(16) float h0b[2][2][10][64];  // [net][row&1][col+1][ch]
  __shared__ __align__(16) float h1b[2][2][10][64];
  __shared__ float red1[4][2][64], red2[4][2][64];   // off-center partials [tap][net][ch]
  __shared__ float redc1[4][2][64], redc2[4][2][64]; // center quarter partials
  __shared__ float xls[256];
  __shared__ float w0a[2][16][64];   // [net][t*4+ic][ch]  (lane-contiguous)
  __shared__ float bza[2][3][64];    // [net][layer][ch]
  __shared__ float woa[2][4][64];    // [net][oc][ch]
  __shared__ float boa[2][4];
  // Occupancy forcer: pushes LDS_Block_Size past 80 KiB so only one block
  // fits per CU (we launch 32 blocks on 256 CUs; >1 block/CU is useless).
  // This aligns the compiler's occupancy target with a 128-VGPR budget.
  __shared__ float lds_occupancy_pad[10752];

  for (int k = tid; k < 9*10*4; k += NT) (&yb[0][0][0])[k] = 0.f;
  for (int k = tid; k < 2*2*10*64; k += NT) {
    (&h0b[0][0][0][0])[k] = 0.f;
    (&h1b[0][0][0][0])[k] = 0.f;
  }
  if (tid < 256) xls[tid] = x[b*256 + tid];          // [c][i][j] flat = c*64 + p

  // keep the pad alive: branch never taken at runtime (b < 32), but the
  // compiler cannot prove it, so the LDS allocation survives.
  if (b >= 1024) {
    lds_occupancy_pad[tid] = x[tid];
    __syncthreads();
    out[0] = lds_occupancy_pad[(tid * 7) & 10751];
  }

  // ---- stage small weights in LDS ----
  {
    const int KHt[4] = {0,0,0,1};
    const int KWt[4] = {0,1,2,0};
    for (int k = tid; k < 2*16*64; k += NT) {        // mask-A taps of w0
      int n = k >> 10, rem = k & 1023;
      int t4ic = rem >> 6, c = rem & 63;
      int t = t4ic >> 2, ic = t4ic & 3;
      const float* w0g = n ? lw0 : mw0;
      w0a[n][t4ic][c] = w0g[((c*4 + ic)*3 + KHt[t])*3 + KWt[t]];
    }
    for (int k = tid; k < 2*3*64; k += NT) {
      int n = k / 192, rem = k % 192, l = rem >> 6, c = rem & 63;
      const float* bp = n ? (l==0 ? lb0 : (l==1 ? lb1 : lb2))
                          : (l==0 ? mb0 : (l==1 ? mb1 : mb2));
      bza[n][l][c] = bp[c];
    }
    for (int k = tid; k < 2*4*64; k += NT) {
      int n = k >> 8, rem = k & 255, oc = rem >> 6, c = rem & 63;
      woa[n][oc][c] = (n ? lwo : mwo)[oc*64 + c];
    }
    if (tid < 8) boa[tid>>2][tid&3] = ((tid>>2) ? lbo : mbo)[tid&3];
  }

  // ---- per-thread register weights (80 floats total) ----
  const float* wg = role ? (net ? lw2 : mw2) : (net ? lw1 : mw1);
  float wcol[64];   // W[ch, :, kh, kw]  (off-center tap column, OIHW)
  float wq[16];     // W[ch, 16*tap .. 16*tap+15, 1, 1]  (center-column quarter)
#pragma unroll
  for (int q = 0; q < 64; ++q) wcol[q] = wg[((ch*64 + q)*3 + kh)*3 + kw];
#pragma unroll
  for (int k = 0; k < 16; ++k)  wq[k] = wg[((ch*64 + 16*tap + k)*3 + 1)*3 + 1];

  __syncthreads();

  float lsacc = 0.f;

#pragma unroll 1
  for (int p = 0; p < 64; ++p) {
    const int i  = p >> 3, j = p & 7;
    const int sl = i & 1;

    // ---- P1: all off-center partials; h0(p) on tid<128
    if (tid < 128) {   // role 0, tap 0
      const int KHt[4] = {0,0,0,1};
      const int KWt[4] = {0,1,2,0};
      float acc = bza[net][0][ch];
#pragma unroll
      for (int t = 0; t < 4; ++t) {
        const float* yv = yb[i + KHt[t]][j + KWt[t]];
        acc += w0a[net][t*4+0][ch]*yv[0] + w0a[net][t*4+1][ch]*yv[1]
             + w0a[net][t*4+2][ch]*yv[2] + w0a[net][t*4+3][ch]*yv[3];
      }
      h0b[net][sl][j + 1][ch] = elu(acc);
    }
    {
      const float* actb = role ? &h1b[net][(i + dr) & 1][j + dc + 1][0]
                               : &h0b[net][(i + dr) & 1][j + dc + 1][0];
      const float4* src = reinterpret_cast<const float4*>(actb);
      float a0 = 0.f, a1 = 0.f, a2 = 0.f, a3 = 0.f;
#pragma unroll
      for (int q = 0; q < 16; ++q) {
        float4 v = src[q];
        a0 += wcol[4*q+0] * v.x; a1 += wcol[4*q+1] * v.y;
        a2 += wcol[4*q+2] * v.z; a3 += wcol[4*q+3] * v.w;
      }
      (role ? red2 : red1)[tap][net][ch] = (a0 + a1) + (a2 + a3);
    }
    __syncthreads();

    // ---- P2: W1-center quarter dots (role 0)
    if (role == 0) {
      const float4* h0p = reinterpret_cast<const float4*>(&h0b[net][sl][j + 1][0]);
      float a0 = 0.f, a1 = 0.f, a2 = 0.f, a3 = 0.f;
#pragma unroll
      for (int kk = 0; kk < 4; ++kk) {
        float4 v = h0p[tap*4 + kk];
        a0 += wq[4*kk+0] * v.x; a1 += wq[4*kk+1] * v.y;
        a2 += wq[4*kk+2] * v.z; a3 += wq[4*kk+3] * v.w;
      }
      redc1[tap][net][ch] = (a0 + a1) + (a2 + a3);
    }
    __syncthreads();

    // ---- P3: h1(p) reduce
    if (tid < 128) {
      float acc = bza[net][1][ch];
#pragma unroll
      for (int t = 0; t < 4; ++t) acc += red1[t][net][ch] + redc1[t][net][ch];
      h1b[net][sl][j + 1][ch] = elu(acc);
    }
    __syncthreads();

    // ---- P4: W2-center quarter dots (role 1)
    if (role == 1) {
      const float4* h1p = reinterpret_cast<const float4*>(&h1b[net][sl][j + 1][0]);
      float a0 = 0.f, a1 = 0.f, a2 = 0.f, a3 = 0.f;
#pragma unroll
      for (int kk = 0; kk < 4; ++kk) {
        float4 v = h1p[tap*4 + kk];
        a0 += wq[4*kk+0] * v.x; a1 += wq[4*kk+1] * v.y;
        a2 += wq[4*kk+2] * v.z; a3 += wq[4*kk+3] * v.w;
      }
      redc2[tap][net][ch] = (a0 + a1) + (a2 + a3);
    }
    __syncthreads();

    // ---- P5: single wave: h2 for BOTH nets + out-conv shuffles + epilogue
    if (tid < 64) {
      float acc0 = bza[0][2][tid];
      float acc1 = bza[1][2][tid];
#pragma unroll
      for (int t = 0; t < 4; ++t) {
        acc0 += red2[t][0][tid] + redc2[t][0][tid];
        acc1 += red2[t][1][tid] + redc2[t][1][tid];
      }
      float h20 = elu(acc0), h21 = elu(acc1);
      float s0 = woa[0][0][tid]*h20, s1 = woa[0][1][tid]*h20;
      float s2 = woa[0][2][tid]*h20, s3 = woa[0][3][tid]*h20;
      float s4 = woa[1][0][tid]*h21, s5 = woa[1][1][tid]*h21;
      float s6 = woa[1][2][tid]*h21, s7 = woa[1][3][tid]*h21;
#pragma unroll
      for (int off = 32; off; off >>= 1) {
        s0 += __shfl_xor(s0, off, 64); s1 += __shfl_xor(s1, off, 64);
        s2 += __shfl_xor(s2, off, 64); s3 += __shfl_xor(s3, off, 64);
        s4 += __shfl_xor(s4, off, 64); s5 += __shfl_xor(s5, off, 64);
        s6 += __shfl_xor(s6, off, 64); s7 += __shfl_xor(s7, off, 64);
      }
      if (tid == 0) {
        float mus[4] = {s0, s1, s2, s3};
        float lss[4] = {s4, s5, s6, s7};
#pragma unroll
        for (int c = 0; c < 4; ++c) {
          float mu = mus[c] + boa[0][c];
          float ls = 0.5f * (lss[c] + boa[1][c]);
          float yv = (xls[c*64 + p] - mu) / (expf(ls) + 1e-12f);
          yb[i + 1][j + 1][c] = yv;
          out[(b*4 + c)*64 + p] = yv;
          lsacc += ls;
        }
      }
    }
    __syncthreads();
  }

  if (tid == 0) out[32*4*64 + b] = lsacc;
}

extern "C" void kernel_launch(void* const* d_in, const int* in_sizes, int n_in,
                              void* d_out, int out_size, void* d_ws, size_t ws_size,
                              hipStream_t stream) {
  (void)in_sizes; (void)n_in; (void)out_size; (void)d_ws; (void)ws_size;
  made_ar_decode_k<<<dim3(32), dim3(NT), 0, stream>>>(
      (const float*)d_in[0],
      (const float*)d_in[1],  (const float*)d_in[2],
      (const float*)d_in[3],  (const float*)d_in[4],
      (const float*)d_in[5],  (const float*)d_in[6],
      (const float*)d_in[7],  (const float*)d_in[8],
      (const float*)d_in[9],  (const float*)d_in[10],
      (const float*)d_in[11], (const float*)d_in[12],
      (const float*)d_in[13], (const float*)d_in[14],
      (const float*)d_in[15], (const float*)d_in[16],
      (float*)d_out);
}

// Round 6
// 283.928 us; speedup vs baseline: 1.0809x; 1.0809x over previous
//
#include <hip/hip_runtime.h>

// MADE / PixelCNN autoregressive inverse (all fp32, per reference):
// one sequential raster decode; each layer computed only at the new pixel
// with cached h0/h1 rows. Bit-exact vs np ref (absmax 0.0, rounds 2-5).
//
// Round-6: VGPR_Count stayed 64 regardless of waves_per_eu/LDS bloat ->
// the machine scheduler SINKS the loop-invariant weight loads into the
// p-loop (L2 re-reads, ~1.7us/step). Fix: pin the off-center weight column
// in registers with empty `asm volatile("" : "+v")` (asm outputs cannot be
// rematerialized), and move the center columns to LDS (w1c/w2c, 32 KB,
// stride-1 conflict-free) so the pinned set is only 64 floats/thread.

#define NT 1024

__device__ __forceinline__ float elu(float x) { return x > 0.f ? x : expm1f(x); }

__global__ __launch_bounds__(NT)
__attribute__((amdgpu_waves_per_eu(4, 4)))
void made_ar_decode_k(
    const float* __restrict__ x,
    const float* __restrict__ mw0, const float* __restrict__ mb0,
    const float* __restrict__ mw1, const float* __restrict__ mb1,
    const float* __restrict__ mw2, const float* __restrict__ mb2,
    const float* __restrict__ mwo, const float* __restrict__ mbo,
    const float* __restrict__ lw0, const float* __restrict__ lb0,
    const float* __restrict__ lw1, const float* __restrict__ lb1,
    const float* __restrict__ lw2, const float* __restrict__ lb2,
    const float* __restrict__ lwo, const float* __restrict__ lbo,
    float* __restrict__ out)
{
  const int b    = blockIdx.x;
  const int tid  = threadIdx.x;
  const int role = tid >> 9;          // 0: W1 / h1-partials, 1: W2 / h2-partials
  const int tap  = (tid >> 7) & 3;    // off-center taps NW,N,NE,W
  const int net  = (tid >> 6) & 1;    // 0 = mu, 1 = lv
  const int ch   = tid & 63;

  // tap -> kernel pos (kh,kw) and spatial offset (dr,dc) = (kh-1, kw-1)
  const int kh = (tap < 3) ? 0 : 1;
  const int kw = (tap < 3) ? tap : 0;
  const int dr = (tap < 3) ? -1 : 0;
  const int dc = (tap < 3) ? (tap - 1) : -1;

  __shared__ __align__(16) float yb[9][10][4];       // rows -1..7 -> 0..8, cols -1..8 -> 0..9 (pads stay 0)
  __shared__ __align__(16) float h0b[2][2][10][64];  // [net][row&1][col+1][ch]
  __shared__ __align__(16) float h1b[2][2][10][64];
  __shared__ float red1[4][2][64], red2[4][2][64];   // off-center partials [tap][net][ch]
  __shared__ float redc1[4][2][64], redc2[4][2][64]; // center quarter partials
  __shared__ float xls[256];
  __shared__ float w0a[2][16][64];   // [net][t*4+ic][ch]  (lane-contiguous)
  __shared__ float w1c[2][64][64];   // center column of W1: [net][k][ch]
  __shared__ float w2c[2][64][64];   // center column of W2: [net][k][ch]
  __shared__ float bza[2][3][64];    // [net][layer][ch]
  __shared__ float woa[2][4][64];    // [net][oc][ch]
  __shared__ float boa[2][4];
  // Occupancy forcer: keeps LDS_Block_Size > 80 KiB so one block/CU
  // (grid is 32 blocks on 256 CUs; >1 block/CU is useless anyway).
  __shared__ float lds_occupancy_pad[2048];

  for (int k = tid; k < 9*10*4; k += NT) (&yb[0][0][0])[k] = 0.f;
  for (int k = tid; k < 2*2*10*64; k += NT) {
    (&h0b[0][0][0][0])[k] = 0.f;
    (&h1b[0][0][0][0])[k] = 0.f;
  }
  if (tid < 256) xls[tid] = x[b*256 + tid];          // [c][i][j] flat = c*64 + p

  // keep the pad alive: branch never taken at runtime (b < 32).
  if (b >= 1024) {
    lds_occupancy_pad[tid & 2047] = x[tid];
    __syncthreads();
    out[0] = lds_occupancy_pad[(tid * 7) & 2047];
  }

  // ---- stage small weights + center columns in LDS ----
  {
    const int KHt[4] = {0,0,0,1};
    const int KWt[4] = {0,1,2,0};
    for (int k = tid; k < 2*16*64; k += NT) {        // mask-A taps of w0
      int n = k >> 10, rem = k & 1023;
      int t4ic = rem >> 6, c = rem & 63;
      int t = t4ic >> 2, ic = t4ic & 3;
      const float* w0g = n ? lw0 : mw0;
      w0a[n][t4ic][c] = w0g[((c*4 + ic)*3 + KHt[t])*3 + KWt[t]];
    }
    for (int k = tid; k < 2*64*64; k += NT) {        // center taps of W1/W2
      int n = k >> 12, rem = k & 4095, q = rem >> 6, c = rem & 63;
      w1c[n][q][c] = (n ? lw1 : mw1)[((c*64 + q)*3 + 1)*3 + 1];
      w2c[n][q][c] = (n ? lw2 : mw2)[((c*64 + q)*3 + 1)*3 + 1];
    }
    for (int k = tid; k < 2*3*64; k += NT) {
      int n = k / 192, rem = k % 192, l = rem >> 6, c = rem & 63;
      const float* bp = n ? (l==0 ? lb0 : (l==1 ? lb1 : lb2))
                          : (l==0 ? mb0 : (l==1 ? mb1 : mb2));
      bza[n][l][c] = bp[c];
    }
    for (int k = tid; k < 2*4*64; k += NT) {
      int n = k >> 8, rem = k & 255, oc = rem >> 6, c = rem & 63;
      woa[n][oc][c] = (n ? lwo : mwo)[oc*64 + c];
    }
    if (tid < 8) boa[tid>>2][tid&3] = ((tid>>2) ? lbo : mbo)[tid&3];
  }

  // ---- per-thread register weights: one off-center tap column, PINNED ----
  const float* wg = role ? (net ? lw2 : mw2) : (net ? lw1 : mw1);
  float wcol[64];   // W[ch, :, kh, kw]  (OIHW)
#pragma unroll
  for (int q = 0; q < 64; ++q) wcol[q] = wg[((ch*64 + q)*3 + kh)*3 + kw];
  // Pin: asm outputs cannot be rematerialized, so the scheduler cannot sink
  // these loads into the p-loop (the round 2-5 failure mode).
#pragma unroll
  for (int q = 0; q < 64; ++q) asm volatile("" : "+v"(wcol[q]));

  __syncthreads();

  float lsacc = 0.f;

#pragma unroll 1
  for (int p = 0; p < 64; ++p) {
    const int i  = p >> 3, j = p & 7;
    const int sl = i & 1;

    // ---- P1: all off-center partials; h0(p) on tid<128
    if (tid < 128) {   // role 0, tap 0
      const int KHt[4] = {0,0,0,1};
      const int KWt[4] = {0,1,2,0};
      float acc = bza[net][0][ch];
#pragma unroll
      for (int t = 0; t < 4; ++t) {
        const float* yv = yb[i + KHt[t]][j + KWt[t]];
        acc += w0a[net][t*4+0][ch]*yv[0] + w0a[net][t*4+1][ch]*yv[1]
             + w0a[net][t*4+2][ch]*yv[2] + w0a[net][t*4+3][ch]*yv[3];
      }
      h0b[net][sl][j + 1][ch] = elu(acc);
    }
    {
      const float* actb = role ? &h1b[net][(i + dr) & 1][j + dc + 1][0]
                               : &h0b[net][(i + dr) & 1][j + dc + 1][0];
      const float4* src = reinterpret_cast<const float4*>(actb);
      float a0 = 0.f, a1 = 0.f, a2 = 0.f, a3 = 0.f;
#pragma unroll
      for (int q = 0; q < 16; ++q) {
        float4 v = src[q];
        a0 += wcol[4*q+0] * v.x; a1 += wcol[4*q+1] * v.y;
        a2 += wcol[4*q+2] * v.z; a3 += wcol[4*q+3] * v.w;
      }
      (role ? red2 : red1)[tap][net][ch] = (a0 + a1) + (a2 + a3);
    }
    __syncthreads();

    // ---- P2: W1-center quarter dots (role 0), weights from LDS
    if (role == 0) {
      const float* h0p = &h0b[net][sl][j + 1][0];
      float a0 = 0.f, a1 = 0.f;
#pragma unroll
      for (int kk = 0; kk < 16; kk += 2) {
        a0 += w1c[net][16*tap + kk    ][ch] * h0p[16*tap + kk    ];
        a1 += w1c[net][16*tap + kk + 1][ch] * h0p[16*tap + kk + 1];
      }
      redc1[tap][net][ch] = a0 + a1;
    }
    __syncthreads();

    // ---- P3: h1(p) reduce
    if (tid < 128) {
      float acc = bza[net][1][ch];
#pragma unroll
      for (int t = 0; t < 4; ++t) acc += red1[t][net][ch] + redc1[t][net][ch];
      h1b[net][sl][j + 1][ch] = elu(acc);
    }
    __syncthreads();

    // ---- P4: W2-center quarter dots (role 1), weights from LDS
    if (role == 1) {
      const float* h1p = &h1b[net][sl][j + 1][0];
      float a0 = 0.f, a1 = 0.f;
#pragma unroll
      for (int kk = 0; kk < 16; kk += 2) {
        a0 += w2c[net][16*tap + kk    ][ch] * h1p[16*tap + kk    ];
        a1 += w2c[net][16*tap + kk + 1][ch] * h1p[16*tap + kk + 1];
      }
      redc2[tap][net][ch] = a0 + a1;
    }
    __syncthreads();

    // ---- P5: single wave: h2 for BOTH nets + out-conv shuffles + epilogue
    if (tid < 64) {
      float acc0 = bza[0][2][tid];
      float acc1 = bza[1][2][tid];
#pragma unroll
      for (int t = 0; t < 4; ++t) {
        acc0 += red2[t][0][tid] + redc2[t][0][tid];
        acc1 += red2[t][1][tid] + redc2[t][1][tid];
      }
      float h20 = elu(acc0), h21 = elu(acc1);
      float s0 = woa[0][0][tid]*h20, s1 = woa[0][1][tid]*h20;
      float s2 = woa[0][2][tid]*h20, s3 = woa[0][3][tid]*h20;
      float s4 = woa[1][0][tid]*h21, s5 = woa[1][1][tid]*h21;
      float s6 = woa[1][2][tid]*h21, s7 = woa[1][3][tid]*h21;
#pragma unroll
      for (int off = 32; off; off >>= 1) {
        s0 += __shfl_xor(s0, off, 64); s1 += __shfl_xor(s1, off, 64);
        s2 += __shfl_xor(s2, off, 64); s3 += __shfl_xor(s3, off, 64);
        s4 += __shfl_xor(s4, off, 64); s5 += __shfl_xor(s5, off, 64);
        s6 += __shfl_xor(s6, off, 64); s7 += __shfl_xor(s7, off, 64);
      }
      if (tid == 0) {
        float mus[4] = {s0, s1, s2, s3};
        float lss[4] = {s4, s5, s6, s7};
#pragma unroll
        for (int c = 0; c < 4; ++c) {
          float mu = mus[c] + boa[0][c];
          float ls = 0.5f * (lss[c] + boa[1][c]);
          float yv = (xls[c*64 + p] - mu) / (expf(ls) + 1e-12f);
          yb[i + 1][j + 1][c] = yv;
          out[(b*4 + c)*64 + p] = yv;
          lsacc += ls;
        }
      }
    }
    __syncthreads();
  }

  if (tid == 0) out[32*4*64 + b] = lsacc;
}

extern "C" void kernel_launch(void* const* d_in, const int* in_sizes, int n_in,
                              void* d_out, int out_size, void* d_ws, size_t ws_size,
                              hipStream_t stream) {
  (void)in_sizes; (void)n_in; (void)out_size; (void)d_ws; (void)ws_size;
  made_ar_decode_k<<<dim3(32), dim3(NT), 0, stream>>>(
      (const float*)d_in[0],
      (const float*)d_in[1],  (const float*)d_in[2],
      (const float*)d_in[3],  (const float*)d_in[4],
      (const float*)d_in[5],  (const float*)d_in[6],
      (const float*)d_in[7],  (const float*)d_in[8],
      (const float*)d_in[9],  (const float*)d_in[10],
      (const float*)d_in[11], (const float*)d_in[12],
      (const float*)d_in[13], (const float*)d_in[14],
      (const float*)d_in[15], (const float*)d_in[16],
      (float*)d_out);
}